// Round 1
// baseline (153.860 us; speedup 1.0000x reference)
//
#include <hip/hip_runtime.h>
#include <hip/hip_bf16.h>

typedef __attribute__((ext_vector_type(8))) short short8;
typedef __attribute__((ext_vector_type(4))) float f32x4;
typedef __attribute__((ext_vector_type(4))) unsigned short u16x4;

__device__ __forceinline__ unsigned short f2bf(float x) {
  unsigned u = __builtin_bit_cast(unsigned, x);
  u += 0x7FFFu + ((u >> 16) & 1u);   // round-to-nearest-even
  return (unsigned short)(u >> 16);
}
__device__ __forceinline__ float bf2f(unsigned short h) {
  return __builtin_bit_cast(float, ((unsigned)h) << 16);
}

// Swizzled LDS index for a 64x64 bf16 matrix.
// 16x 4-element (8B) units per row; physical unit = unit ^ (row&15).
// Keeps the 8B fragment reads (16 lanes, consecutive rows, same col) on
// 16 distinct 2-bank windows -> conflict-free.
__device__ __forceinline__ int sidx(int row, int col) {
  return (row << 6) + ((((col >> 2) ^ (row & 15))) << 2) + (col & 3);
}

// A/B fragment for v_mfma_f32_16x16x32_bf16:
// elem e (0..7): k = kbase + 16*(e>>2) + 4*hi + (e&3), row/col = per-lane.
__device__ __forceinline__ short8 ldfrag(const unsigned short* m, int row, int kbase, int hi) {
  const int c0 = kbase + (hi << 2);
  const int rb = (row << 6);
  const int rx = row & 15;
  u16x4 a = *(const u16x4*)(m + rb + ((((c0) >> 2) ^ rx) << 2));
  u16x4 b = *(const u16x4*)(m + rb + ((((c0 + 16) >> 2) ^ rx) << 2));
  short8 f;
  f[0] = (short)a[0]; f[1] = (short)a[1]; f[2] = (short)a[2]; f[3] = (short)a[3];
  f[4] = (short)b[0]; f[5] = (short)b[1]; f[6] = (short)b[2]; f[7] = (short)b[3];
  return f;
}

__global__ __launch_bounds__(256, 3) void attn64_kernel(
    const float* __restrict__ qg, const float* __restrict__ kg,
    const float* __restrict__ vg, const float* __restrict__ pg,
    const float* __restrict__ rg, float* __restrict__ og) {
  __shared__ unsigned short sm[6 * 4096];  // 48 KiB
  unsigned short* qh = sm + 0;       // q hi (bf16)
  unsigned short* ql = sm + 4096;    // q lo
  unsigned short* kh = sm + 8192;    // k hi
  unsigned short* kl = sm + 12288;   // k lo
  unsigned short* vt = sm + 16384;   // v transposed (vt[n][k] = v[k][n])
  unsigned short* pt = sm + 20480;   // proj transposed
  unsigned short* eb = sm + 0;       // exp(scores), reuses qh after barrier
  unsigned short* cb = sm + 4096;    // ctx, reuses ql

  const int tid = threadIdx.x;
  const size_t base = (size_t)blockIdx.x << 12;  // tile offset in elements

  const float4* q4 = (const float4*)(qg + base);
  const float4* k4 = (const float4*)(kg + base);
  const float4* v4 = (const float4*)(vg + base);
  const float4* p4 = (const float4*)(pg + base);

  // ---- stage: q,k -> hi/lo bf16; v,proj -> transposed bf16 ----
  #pragma unroll
  for (int it = 0; it < 4; ++it) {
    const int i4 = tid + (it << 8);   // float4 index 0..1023
    const int row = i4 >> 4;
    const int c4 = i4 & 15;
    const int un = (c4 ^ (row & 15)) << 2;
    {
      float4 x = q4[i4];
      unsigned short h0 = f2bf(x.x), h1 = f2bf(x.y), h2 = f2bf(x.z), h3 = f2bf(x.w);
      u16x4 hv = {h0, h1, h2, h3};
      u16x4 lv = {f2bf(x.x - bf2f(h0)), f2bf(x.y - bf2f(h1)),
                  f2bf(x.z - bf2f(h2)), f2bf(x.w - bf2f(h3))};
      *(u16x4*)(qh + (row << 6) + un) = hv;
      *(u16x4*)(ql + (row << 6) + un) = lv;
    }
    {
      float4 x = k4[i4];
      unsigned short h0 = f2bf(x.x), h1 = f2bf(x.y), h2 = f2bf(x.z), h3 = f2bf(x.w);
      u16x4 hv = {h0, h1, h2, h3};
      u16x4 lv = {f2bf(x.x - bf2f(h0)), f2bf(x.y - bf2f(h1)),
                  f2bf(x.z - bf2f(h2)), f2bf(x.w - bf2f(h3))};
      *(u16x4*)(kh + (row << 6) + un) = hv;
      *(u16x4*)(kl + (row << 6) + un) = lv;
    }
    {
      float4 x = v4[i4];
      const int r2 = c4 << 2;
      vt[sidx(r2 + 0, row)] = f2bf(x.x);
      vt[sidx(r2 + 1, row)] = f2bf(x.y);
      vt[sidx(r2 + 2, row)] = f2bf(x.z);
      vt[sidx(r2 + 3, row)] = f2bf(x.w);
    }
    {
      float4 x = p4[i4];
      const int r2 = c4 << 2;
      pt[sidx(r2 + 0, row)] = f2bf(x.x);
      pt[sidx(r2 + 1, row)] = f2bf(x.y);
      pt[sidx(r2 + 2, row)] = f2bf(x.z);
      pt[sidx(r2 + 3, row)] = f2bf(x.w);
    }
  }
  __syncthreads();

  const int l = tid & 63;
  const int w = tid >> 6;     // wave -> row band [16w, 16w+16)
  const int lo = l & 15;
  const int hi = l >> 4;
  const int arow = (w << 4) + lo;

  // ---- scores = q @ k^T with bf16 hi/lo split (hh + lh + hl) ----
  short8 aH0 = ldfrag(qh, arow, 0, hi);
  short8 aH1 = ldfrag(qh, arow, 32, hi);
  short8 aL0 = ldfrag(ql, arow, 0, hi);
  short8 aL1 = ldfrag(ql, arow, 32, hi);

  float et[4][4];
  #pragma unroll
  for (int t = 0; t < 4; ++t) {
    f32x4 acc = {0.f, 0.f, 0.f, 0.f};
    const int brow = (t << 4) + lo;
    short8 bH0 = ldfrag(kh, brow, 0, hi);
    short8 bL0 = ldfrag(kl, brow, 0, hi);
    acc = __builtin_amdgcn_mfma_f32_16x16x32_bf16(aH0, bH0, acc, 0, 0, 0);
    acc = __builtin_amdgcn_mfma_f32_16x16x32_bf16(aL0, bH0, acc, 0, 0, 0);
    acc = __builtin_amdgcn_mfma_f32_16x16x32_bf16(aH0, bL0, acc, 0, 0, 0);
    short8 bH1 = ldfrag(kh, brow, 32, hi);
    short8 bL1 = ldfrag(kl, brow, 32, hi);
    acc = __builtin_amdgcn_mfma_f32_16x16x32_bf16(aH1, bH1, acc, 0, 0, 0);
    acc = __builtin_amdgcn_mfma_f32_16x16x32_bf16(aL1, bH1, acc, 0, 0, 0);
    acc = __builtin_amdgcn_mfma_f32_16x16x32_bf16(aH1, bL1, acc, 0, 0, 0);
    #pragma unroll
    for (int j = 0; j < 4; ++j) et[t][j] = __expf(acc[j]);
  }

  // ---- row sums: butterfly over the 16-lane column groups ----
  float rs[4];
  #pragma unroll
  for (int j = 0; j < 4; ++j) rs[j] = (et[0][j] + et[1][j]) + (et[2][j] + et[3][j]);
  #pragma unroll
  for (int m = 1; m < 16; m <<= 1) {
    #pragma unroll
    for (int j = 0; j < 4; ++j) rs[j] += __shfl_xor(rs[j], m, 64);
  }
  float rinv[4];
  #pragma unroll
  for (int j = 0; j < 4; ++j) rinv[j] = 1.0f / rs[j];

  __syncthreads();  // all waves done reading qh/ql/kh/kl before overwrite

  // ---- write unnormalized e (bf16); normalization folded in after PV ----
  #pragma unroll
  for (int t = 0; t < 4; ++t) {
    #pragma unroll
    for (int j = 0; j < 4; ++j) {
      eb[sidx((w << 4) + (hi << 2) + j, (t << 4) + lo)] = f2bf(et[t][j]);
    }
  }
  __syncthreads();

  // ---- ctx = (e @ v) * rinv ----
  short8 ae0 = ldfrag(eb, arow, 0, hi);
  short8 ae1 = ldfrag(eb, arow, 32, hi);
  float ctx[4][4];
  #pragma unroll
  for (int t = 0; t < 4; ++t) {
    f32x4 acc = {0.f, 0.f, 0.f, 0.f};
    const int brow = (t << 4) + lo;
    short8 b0 = ldfrag(vt, brow, 0, hi);
    short8 b1 = ldfrag(vt, brow, 32, hi);
    acc = __builtin_amdgcn_mfma_f32_16x16x32_bf16(ae0, b0, acc, 0, 0, 0);
    acc = __builtin_amdgcn_mfma_f32_16x16x32_bf16(ae1, b1, acc, 0, 0, 0);
    #pragma unroll
    for (int j = 0; j < 4; ++j) ctx[t][j] = acc[j] * rinv[j];
  }

  // ---- write ctx (bf16) ----
  #pragma unroll
  for (int t = 0; t < 4; ++t) {
    #pragma unroll
    for (int j = 0; j < 4; ++j) {
      cb[sidx((w << 4) + (hi << 2) + j, (t << 4) + lo)] = f2bf(ctx[t][j]);
    }
  }
  __syncthreads();

  // ---- out = ctx @ proj + residual ----
  short8 ac0 = ldfrag(cb, arow, 0, hi);
  short8 ac1 = ldfrag(cb, arow, 32, hi);
  #pragma unroll
  for (int t = 0; t < 4; ++t) {
    f32x4 acc = {0.f, 0.f, 0.f, 0.f};
    const int brow = (t << 4) + lo;
    short8 b0 = ldfrag(pt, brow, 0, hi);
    short8 b1 = ldfrag(pt, brow, 32, hi);
    acc = __builtin_amdgcn_mfma_f32_16x16x32_bf16(ac0, b0, acc, 0, 0, 0);
    acc = __builtin_amdgcn_mfma_f32_16x16x32_bf16(ac1, b1, acc, 0, 0, 0);
    #pragma unroll
    for (int j = 0; j < 4; ++j) {
      const int off = (((w << 4) + (hi << 2) + j) << 6) + (t << 4) + lo;
      og[base + off] = acc[j] + rg[base + off];
    }
  }
}

extern "C" void kernel_launch(void* const* d_in, const int* in_sizes, int n_in,
                              void* d_out, int out_size, void* d_ws, size_t ws_size,
                              hipStream_t stream) {
  const float* q = (const float*)d_in[0];
  const float* k = (const float*)d_in[1];
  const float* v = (const float*)d_in[2];
  const float* p = (const float*)d_in[3];
  const float* r = (const float*)d_in[4];
  float* o = (float*)d_out;
  const int B = in_sizes[0] >> 12;  // tiles of 64*64
  attn64_kernel<<<dim3(B), dim3(256), 0, stream>>>(q, k, v, p, r, o);
}

// Round 3
// 152.012 us; speedup vs baseline: 1.0122x; 1.0122x over previous
//
#include <hip/hip_runtime.h>
#include <hip/hip_bf16.h>

typedef __attribute__((ext_vector_type(8))) short short8;
typedef __attribute__((ext_vector_type(4))) float f32x4;
typedef __attribute__((ext_vector_type(4))) unsigned short u16x4;

__device__ __forceinline__ unsigned short f2bf(float x) {
  unsigned u = __builtin_bit_cast(unsigned, x);
  u += 0x7FFFu + ((u >> 16) & 1u);   // round-to-nearest-even
  return (unsigned short)(u >> 16);
}
__device__ __forceinline__ float bf2f(unsigned short h) {
  return __builtin_bit_cast(float, ((unsigned)h) << 16);
}

// Swizzle hash: 16 distinct values both for fragment reads (rows 16t+lo,
// lo varying -> h = lo^t) and transposed writes (rows 4*c4+j, c4 varying ->
// bits[3:2]=c4&3, bits[1:0]=j^(c4>>2)). Both access walks conflict-free.
__device__ __forceinline__ int hsw(int row) { return (row & 15) ^ ((row >> 4) & 3); }
__device__ __forceinline__ int sidx(int row, int col) {
  return (row << 6) + ((((col >> 2) ^ hsw(row)) & 15) << 2) + (col & 3);
}

// A/B fragment for v_mfma_f32_16x16x32_bf16:
// elem e (0..7): k = kbase + 16*(e>>2) + 4*hi + (e&3).
__device__ __forceinline__ short8 ldfrag(const unsigned short* m, int row, int kbase, int hi) {
  const int c0 = kbase + (hi << 2);
  const int rb = row << 6;
  const int hx = hsw(row);
  u16x4 a = *(const u16x4*)(m + rb + ((((c0 >> 2) ^ hx) & 15) << 2));
  u16x4 b = *(const u16x4*)(m + rb + (((((c0 + 16) >> 2) ^ hx) & 15) << 2));
  short8 f;
  f[0] = (short)a[0]; f[1] = (short)a[1]; f[2] = (short)a[2]; f[3] = (short)a[3];
  f[4] = (short)b[0]; f[5] = (short)b[1]; f[6] = (short)b[2]; f[7] = (short)b[3];
  return f;
}

// hi/lo bf16 split of 4 floats into fragment slots [o, o+4)
__device__ __forceinline__ void split4(float4 v, short8& H, short8& L, int o) {
  unsigned short h0 = f2bf(v.x), h1 = f2bf(v.y), h2 = f2bf(v.z), h3 = f2bf(v.w);
  H[o + 0] = (short)h0; H[o + 1] = (short)h1; H[o + 2] = (short)h2; H[o + 3] = (short)h3;
  L[o + 0] = (short)f2bf(v.x - bf2f(h0));
  L[o + 1] = (short)f2bf(v.y - bf2f(h1));
  L[o + 2] = (short)f2bf(v.z - bf2f(h2));
  L[o + 3] = (short)f2bf(v.w - bf2f(h3));
}

__global__ __launch_bounds__(256, 5) void attn64_kernel(
    const float* __restrict__ qg, const float* __restrict__ kg,
    const float* __restrict__ vg, const float* __restrict__ pg,
    const float* __restrict__ rg, float* __restrict__ og) {
  __shared__ unsigned short sm[4 * 4096];  // 32 KiB -> 5 blocks/CU
  unsigned short* kh = sm + 0;       // k hi (bf16)
  unsigned short* kl = sm + 4096;    // k lo
  unsigned short* vt = sm + 8192;    // v transposed
  unsigned short* pt = sm + 12288;   // proj transposed
  unsigned short* eb = sm + 0;       // exp(scores), reuses kh after barrier
  unsigned short* cb = sm + 4096;    // ctx, reuses kl

  const int tid = threadIdx.x;
  const size_t base = (size_t)blockIdx.x << 12;

  const float4* k4 = (const float4*)(kg + base);
  const float4* v4 = (const float4*)(vg + base);
  const float4* p4 = (const float4*)(pg + base);

  const int l = tid & 63;
  const int w = tid >> 6;
  const int lo = l & 15;
  const int hi = l >> 4;
  const int arow = (w << 4) + lo;

  // ---- q: load this wave's rows straight into registers (no LDS) ----
  const float* qrow = qg + base + ((size_t)arow << 6);
  float4 xq0 = *(const float4*)(qrow + (hi << 2));
  float4 xq1 = *(const float4*)(qrow + 16 + (hi << 2));
  float4 xq2 = *(const float4*)(qrow + 32 + (hi << 2));
  float4 xq3 = *(const float4*)(qrow + 48 + (hi << 2));

  // ---- stage: k -> hi/lo bf16; v,proj -> transposed bf16 ----
  #pragma unroll
  for (int it = 0; it < 4; ++it) {
    const int i4 = tid + (it << 8);
    const int row = i4 >> 4;
    const int c4 = i4 & 15;
    const int un = ((c4 ^ hsw(row)) & 15) << 2;
    {
      float4 x = k4[i4];
      unsigned short h0 = f2bf(x.x), h1 = f2bf(x.y), h2 = f2bf(x.z), h3 = f2bf(x.w);
      u16x4 hv = {h0, h1, h2, h3};
      u16x4 lv = {f2bf(x.x - bf2f(h0)), f2bf(x.y - bf2f(h1)),
                  f2bf(x.z - bf2f(h2)), f2bf(x.w - bf2f(h3))};
      *(u16x4*)(kh + (row << 6) + un) = hv;
      *(u16x4*)(kl + (row << 6) + un) = lv;
    }
    {
      float4 x = v4[i4];
      const int r2 = c4 << 2;
      vt[sidx(r2 + 0, row)] = f2bf(x.x);
      vt[sidx(r2 + 1, row)] = f2bf(x.y);
      vt[sidx(r2 + 2, row)] = f2bf(x.z);
      vt[sidx(r2 + 3, row)] = f2bf(x.w);
    }
    {
      float4 x = p4[i4];
      const int r2 = c4 << 2;
      pt[sidx(r2 + 0, row)] = f2bf(x.x);
      pt[sidx(r2 + 1, row)] = f2bf(x.y);
      pt[sidx(r2 + 2, row)] = f2bf(x.z);
      pt[sidx(r2 + 3, row)] = f2bf(x.w);
    }
  }

  // ---- q hi/lo split in-register (overlaps with staging-load latency) ----
  short8 aH0, aL0, aH1, aL1;
  split4(xq0, aH0, aL0, 0);
  split4(xq1, aH0, aL0, 4);
  split4(xq2, aH1, aL1, 0);
  split4(xq3, aH1, aL1, 4);

  __syncthreads();

  // ---- scores = q @ k^T with bf16 hi/lo split (hh + lh + hl) ----
  float et[4][4];
  #pragma unroll
  for (int t = 0; t < 4; ++t) {
    f32x4 acc = {0.f, 0.f, 0.f, 0.f};
    const int brow = (t << 4) + lo;
    short8 bH0 = ldfrag(kh, brow, 0, hi);
    short8 bL0 = ldfrag(kl, brow, 0, hi);
    acc = __builtin_amdgcn_mfma_f32_16x16x32_bf16(aH0, bH0, acc, 0, 0, 0);
    acc = __builtin_amdgcn_mfma_f32_16x16x32_bf16(aL0, bH0, acc, 0, 0, 0);
    acc = __builtin_amdgcn_mfma_f32_16x16x32_bf16(aH0, bL0, acc, 0, 0, 0);
    short8 bH1 = ldfrag(kh, brow, 32, hi);
    short8 bL1 = ldfrag(kl, brow, 32, hi);
    acc = __builtin_amdgcn_mfma_f32_16x16x32_bf16(aH1, bH1, acc, 0, 0, 0);
    acc = __builtin_amdgcn_mfma_f32_16x16x32_bf16(aL1, bH1, acc, 0, 0, 0);
    acc = __builtin_amdgcn_mfma_f32_16x16x32_bf16(aH1, bL1, acc, 0, 0, 0);
    #pragma unroll
    for (int j = 0; j < 4; ++j) et[t][j] = __expf(acc[j]);
  }

  // ---- row sums: butterfly over the 16-lane column groups ----
  float rs[4];
  #pragma unroll
  for (int j = 0; j < 4; ++j) rs[j] = (et[0][j] + et[1][j]) + (et[2][j] + et[3][j]);
  #pragma unroll
  for (int m = 1; m < 16; m <<= 1) {
    #pragma unroll
    for (int j = 0; j < 4; ++j) rs[j] += __shfl_xor(rs[j], m, 64);
  }
  float rinv[4];
  #pragma unroll
  for (int j = 0; j < 4; ++j) rinv[j] = 1.0f / rs[j];

  __syncthreads();  // all waves done reading kh/kl before overwrite

  // ---- write unnormalized e (bf16); normalization folded in after PV ----
  #pragma unroll
  for (int t = 0; t < 4; ++t) {
    #pragma unroll
    for (int j = 0; j < 4; ++j) {
      eb[sidx((w << 4) + (hi << 2) + j, (t << 4) + lo)] = f2bf(et[t][j]);
    }
  }
  __syncthreads();

  // ---- ctx = (e @ v) * rinv ----
  short8 ae0 = ldfrag(eb, arow, 0, hi);
  short8 ae1 = ldfrag(eb, arow, 32, hi);
  float ctx[4][4];
  #pragma unroll
  for (int t = 0; t < 4; ++t) {
    f32x4 acc = {0.f, 0.f, 0.f, 0.f};
    const int brow = (t << 4) + lo;
    short8 b0 = ldfrag(vt, brow, 0, hi);
    short8 b1 = ldfrag(vt, brow, 32, hi);
    acc = __builtin_amdgcn_mfma_f32_16x16x32_bf16(ae0, b0, acc, 0, 0, 0);
    acc = __builtin_amdgcn_mfma_f32_16x16x32_bf16(ae1, b1, acc, 0, 0, 0);
    #pragma unroll
    for (int j = 0; j < 4; ++j) ctx[t][j] = acc[j] * rinv[j];
  }

  // ---- write ctx (bf16) ----
  #pragma unroll
  for (int t = 0; t < 4; ++t) {
    #pragma unroll
    for (int j = 0; j < 4; ++j) {
      cb[sidx((w << 4) + (hi << 2) + j, (t << 4) + lo)] = f2bf(ctx[t][j]);
    }
  }
  __syncthreads();

  // ---- out = ctx @ proj + residual ----
  short8 ac0 = ldfrag(cb, arow, 0, hi);
  short8 ac1 = ldfrag(cb, arow, 32, hi);
  #pragma unroll
  for (int t = 0; t < 4; ++t) {
    f32x4 acc = {0.f, 0.f, 0.f, 0.f};
    const int brow = (t << 4) + lo;
    short8 b0 = ldfrag(pt, brow, 0, hi);
    short8 b1 = ldfrag(pt, brow, 32, hi);
    acc = __builtin_amdgcn_mfma_f32_16x16x32_bf16(ac0, b0, acc, 0, 0, 0);
    acc = __builtin_amdgcn_mfma_f32_16x16x32_bf16(ac1, b1, acc, 0, 0, 0);
    #pragma unroll
    for (int j = 0; j < 4; ++j) {
      const int off = (((w << 4) + (hi << 2) + j) << 6) + (t << 4) + lo;
      og[base + off] = acc[j] + rg[base + off];
    }
  }
}

extern "C" void kernel_launch(void* const* d_in, const int* in_sizes, int n_in,
                              void* d_out, int out_size, void* d_ws, size_t ws_size,
                              hipStream_t stream) {
  const float* q = (const float*)d_in[0];
  const float* k = (const float*)d_in[1];
  const float* v = (const float*)d_in[2];
  const float* p = (const float*)d_in[3];
  const float* r = (const float*)d_in[4];
  float* o = (float*)d_out;
  const int B = in_sizes[0] >> 12;  // tiles of 64*64
  attn64_kernel<<<dim3(B), dim3(256), 0, stream>>>(q, k, v, p, r, o);
}